// Round 9
// baseline (360.760 us; speedup 1.0000x reference)
//
#include <hip/hip_runtime.h>

// GraphSAGE 2-layer, N=50000, E=800000, 64 -> 128 -> 64, fp32.
//   h   = relu(mean_agg(x) @ W1_l + b1 + x @ W1_r)
//   out = mean_agg(h) @ W2_l + b2 + h @ W2_r
// R9:
//  - gather: 16-lane group owns a full node row; colsrc rows 16B-aligned so
//    indices load as int4 (1 broadcast load -> 4 indices -> 4 independent
//    256B row loads; windows of 8 in flight). No shfl reduce (lane owns cols).
//  - dense: 64 nodes/block, 8n x 4j register tile (256 FMA per 16 loads),
//    phase-2 node-interleaved (node = g2 + 8m) for conflict-free hs reads.
//  - gather1 fused into k_layer1 (mean -> LDS only); layer2 = gather+epilogue.
// Linearity: mean_agg(h)@W2_l = agg(h@W2_l)/cnt -> layer 2 gathers p = h@W2_l.

#define FMA4(acc, f, w0, w1, w2, w3)                          \
  acc.x += f.x * w0.x + f.y * w1.x + f.z * w2.x + f.w * w3.x; \
  acc.y += f.x * w0.y + f.y * w1.y + f.z * w2.y + f.w * w3.y; \
  acc.z += f.x * w0.z + f.y * w1.z + f.z * w2.z + f.w * w3.z; \
  acc.w += f.x * w0.w + f.y * w1.w + f.z * w2.w + f.w * w3.w;

// ---------------- CSR build (scan-free, 16B-aligned rows) ----------------
__global__ __launch_bounds__(256) void k_hist(const int* __restrict__ dst,
                                              int* __restrict__ deg, int E) {
  int e = blockIdx.x * blockDim.x + threadIdx.x;
  if (e < E) atomicAdd(&deg[dst[e]], 1);
}

__global__ __launch_bounds__(256) void k_assign(const int* __restrict__ deg,
                                                int* __restrict__ rowptr,
                                                int* __restrict__ pos,
                                                int* __restrict__ total,
                                                int N) {
  int i = blockIdx.x * blockDim.x + threadIdx.x;
  if (i >= N) return;
  int d4 = (deg[i] + 3) & ~3;  // 16B-aligned row
  int r = atomicAdd(total, d4);
  rowptr[i] = r;
  pos[i] = r;
}

__global__ __launch_bounds__(256) void k_fill(const int* __restrict__ src,
                                              const int* __restrict__ dst,
                                              int* __restrict__ pos,
                                              int* __restrict__ colsrc, int E) {
  int e = blockIdx.x * blockDim.x + threadIdx.x;
  if (e >= E) return;
  int slot = atomicAdd(&pos[dst[e]], 1);
  colsrc[slot] = src[e];
}

// ---------------------------------------------------------------------------
// layer1: 64 nodes/block, 256 threads.
//   gather (to LDS): group g (16 lanes) sums rows of its 4 nodes; int4 index
//     windows -> 8 row loads in flight; lane owns 4 cols, no reduce.
//   phase1: thread (jt=tid&31, nt=tid>>5) -> 8n x 4j tile of h (k unroll 4).
//   phase2: waves 0-1 p=h@W2l, waves 2-3 q=h@W2r; node = g2 + 8m interleave.
// LDS: ms[64][68]+xs[64][68] (34.8KB) overlaid by hs[64][132] (33.8KB).
// ---------------------------------------------------------------------------
__global__ __launch_bounds__(256, 4) void k_layer1(
    const float* __restrict__ x, const int* __restrict__ rowptr,
    const int* __restrict__ deg, const int* __restrict__ colsrc,
    const float* __restrict__ W1l, const float* __restrict__ b1,
    const float* __restrict__ W1r, const float* __restrict__ W2l,
    const float* __restrict__ W2r, float* __restrict__ p,
    float* __restrict__ q, int N) {
  int i0 = blockIdx.x * 64;
  int tid = threadIdx.x;
  __shared__ float smem[64 * 68 * 2];               // 34816 B
  float(*ms)[68] = (float(*)[68])smem;              // [64][68]
  float(*xs)[68] = (float(*)[68])(smem + 64 * 68);  // [64][68]
  float(*hs)[132] = (float(*)[132])smem;            // overlays after sync

  // ---- gather phase: mean -> ms (group of 16 lanes per node) ----
  {
    int grp = tid >> 4;             // 0..15
    int c4 = (tid & 15) << 2;       // 0,4,...,60
    for (int nn = 0; nn < 4; ++nn) {
      int nl = grp * 4 + nn;        // local node 0..63
      int node = i0 + nl;
      float4 s0 = make_float4(0.f, 0.f, 0.f, 0.f);
      float4 s1 = s0, s2 = s0, s3 = s0;
      float rd = 0.f;
      if (node < N) {
        int base = rowptr[node];
        int d = deg[node];
        rd = 1.f / fmaxf((float)d, 1.f);
        int i = 0;
        for (; i + 8 <= d; i += 8) {
          int4 ia = *(const int4*)&colsrc[base + i];
          int4 ib = *(const int4*)&colsrc[base + i + 4];
          float4 v0 = *(const float4*)&x[(size_t)ia.x * 64 + c4];
          float4 v1 = *(const float4*)&x[(size_t)ia.y * 64 + c4];
          float4 v2 = *(const float4*)&x[(size_t)ia.z * 64 + c4];
          float4 v3 = *(const float4*)&x[(size_t)ia.w * 64 + c4];
          float4 v4 = *(const float4*)&x[(size_t)ib.x * 64 + c4];
          float4 v5 = *(const float4*)&x[(size_t)ib.y * 64 + c4];
          float4 v6 = *(const float4*)&x[(size_t)ib.z * 64 + c4];
          float4 v7 = *(const float4*)&x[(size_t)ib.w * 64 + c4];
          s0.x += v0.x; s0.y += v0.y; s0.z += v0.z; s0.w += v0.w;
          s1.x += v1.x; s1.y += v1.y; s1.z += v1.z; s1.w += v1.w;
          s2.x += v2.x; s2.y += v2.y; s2.z += v2.z; s2.w += v2.w;
          s3.x += v3.x; s3.y += v3.y; s3.z += v3.z; s3.w += v3.w;
          s0.x += v4.x; s0.y += v4.y; s0.z += v4.z; s0.w += v4.w;
          s1.x += v5.x; s1.y += v5.y; s1.z += v5.z; s1.w += v5.w;
          s2.x += v6.x; s2.y += v6.y; s2.z += v6.z; s2.w += v6.w;
          s3.x += v7.x; s3.y += v7.y; s3.z += v7.z; s3.w += v7.w;
        }
        for (; i < d; ++i) {
          int idx = colsrc[base + i];
          float4 v = *(const float4*)&x[(size_t)idx * 64 + c4];
          s0.x += v.x; s0.y += v.y; s0.z += v.z; s0.w += v.w;
        }
      }
      s0.x = (s0.x + s1.x + s2.x + s3.x) * rd;
      s0.y = (s0.y + s1.y + s2.y + s3.y) * rd;
      s0.z = (s0.z + s1.z + s2.z + s3.z) * rd;
      s0.w = (s0.w + s1.w + s2.w + s3.w) * rd;
      *(float4*)&ms[nl][c4] = s0;
    }
  }
  // stage xs: 64 nodes x 16 float4 = 1024 float4 across 256 threads
  for (int t = tid; t < 1024; t += 256) {
    int n = t >> 4;
    int c4 = (t & 15) << 2;
    int node = i0 + n;
    float4 zx = make_float4(0.f, 0.f, 0.f, 0.f);
    if (node < N) zx = *(const float4*)&x[(size_t)node * 64 + c4];
    *(float4*)&xs[n][c4] = zx;
  }
  __syncthreads();

  // ---- phase 1: h tile (8 nodes x 4 cols per thread) ----
  int jt = tid & 31;
  int j0 = jt << 2;          // 0..124
  int nt = tid >> 5;
  int n0 = nt << 3;          // 0..56
  float4 acc[8];
  {
    float4 bj = *(const float4*)&b1[j0];
#pragma unroll
    for (int n = 0; n < 8; ++n) acc[n] = bj;
  }
#pragma unroll 2
  for (int k0 = 0; k0 < 64; k0 += 4) {
    float4 wl[4], wr[4];
#pragma unroll
    for (int kk = 0; kk < 4; ++kk) {
      wl[kk] = *(const float4*)&W1l[(size_t)(k0 + kk) * 128 + j0];
      wr[kk] = *(const float4*)&W1r[(size_t)(k0 + kk) * 128 + j0];
    }
#pragma unroll
    for (int n = 0; n < 8; ++n) {
      float4 m4 = *(const float4*)&ms[n0 + n][k0];
      float4 x4 = *(const float4*)&xs[n0 + n][k0];
      FMA4(acc[n], m4, wl[0], wl[1], wl[2], wl[3]);
      FMA4(acc[n], x4, wr[0], wr[1], wr[2], wr[3]);
    }
  }
  __syncthreads();  // ms/xs reads done before hs overlay

#pragma unroll
  for (int n = 0; n < 8; ++n) {
    float4 v = acc[n];
    v.x = fmaxf(v.x, 0.f);
    v.y = fmaxf(v.y, 0.f);
    v.z = fmaxf(v.z, 0.f);
    v.w = fmaxf(v.w, 0.f);
    *(float4*)&hs[n0 + n][j0] = v;
  }
  __syncthreads();

  // ---- phase 2: p = hs@W2l (waves 0-1), q = hs@W2r (waves 2-3) ----
  const float* W = (tid < 128) ? W2l : W2r;
  float* ob = (tid < 128) ? p : q;
  int t2 = tid & 127;
  int jj0 = (t2 & 15) << 2;  // 0..60
  int g2 = t2 >> 4;          // 0..7 ; nodes g2 + 8m (interleaved, bank-free)
  float4 pa[8];
#pragma unroll
  for (int n = 0; n < 8; ++n) pa[n] = make_float4(0.f, 0.f, 0.f, 0.f);
#pragma unroll 2
  for (int k0 = 0; k0 < 128; k0 += 4) {
    float4 w[4];
#pragma unroll
    for (int kk = 0; kk < 4; ++kk)
      w[kk] = *(const float4*)&W[(size_t)(k0 + kk) * 64 + jj0];
#pragma unroll
    for (int m = 0; m < 8; ++m) {
      float4 h4 = *(const float4*)&hs[g2 + 8 * m][k0];
      FMA4(pa[m], h4, w[0], w[1], w[2], w[3]);
    }
  }
#pragma unroll
  for (int m = 0; m < 8; ++m) {
    int node = i0 + g2 + 8 * m;
    if (node < N) *(float4*)&ob[(size_t)node * 64 + jj0] = pa[m];
  }
}

// ---------------------------------------------------------------------------
// layer2: out[node] = mean_agg(p)[node] + q[node] + b2.
// 16-lane group per node, int4 index windows, 8 row loads in flight.
// ---------------------------------------------------------------------------
__global__ __launch_bounds__(256) void k_layer2(
    const float* __restrict__ p, const int* __restrict__ rowptr,
    const int* __restrict__ deg, const int* __restrict__ colsrc,
    const float* __restrict__ q, const float* __restrict__ b2,
    float* __restrict__ out, int N) {
  int node = blockIdx.x * 16 + (threadIdx.x >> 4);
  if (node >= N) return;
  int c4 = (threadIdx.x & 15) << 2;
  int base = rowptr[node];
  int d = deg[node];
  float4 s0 = make_float4(0.f, 0.f, 0.f, 0.f);
  float4 s1 = s0, s2 = s0, s3 = s0;
  int i = 0;
  for (; i + 8 <= d; i += 8) {
    int4 ia = *(const int4*)&colsrc[base + i];
    int4 ib = *(const int4*)&colsrc[base + i + 4];
    float4 v0 = *(const float4*)&p[(size_t)ia.x * 64 + c4];
    float4 v1 = *(const float4*)&p[(size_t)ia.y * 64 + c4];
    float4 v2 = *(const float4*)&p[(size_t)ia.z * 64 + c4];
    float4 v3 = *(const float4*)&p[(size_t)ia.w * 64 + c4];
    float4 v4 = *(const float4*)&p[(size_t)ib.x * 64 + c4];
    float4 v5 = *(const float4*)&p[(size_t)ib.y * 64 + c4];
    float4 v6 = *(const float4*)&p[(size_t)ib.z * 64 + c4];
    float4 v7 = *(const float4*)&p[(size_t)ib.w * 64 + c4];
    s0.x += v0.x; s0.y += v0.y; s0.z += v0.z; s0.w += v0.w;
    s1.x += v1.x; s1.y += v1.y; s1.z += v1.z; s1.w += v1.w;
    s2.x += v2.x; s2.y += v2.y; s2.z += v2.z; s2.w += v2.w;
    s3.x += v3.x; s3.y += v3.y; s3.z += v3.z; s3.w += v3.w;
    s0.x += v4.x; s0.y += v4.y; s0.z += v4.z; s0.w += v4.w;
    s1.x += v5.x; s1.y += v5.y; s1.z += v5.z; s1.w += v5.w;
    s2.x += v6.x; s2.y += v6.y; s2.z += v6.z; s2.w += v6.w;
    s3.x += v7.x; s3.y += v7.y; s3.z += v7.z; s3.w += v7.w;
  }
  for (; i < d; ++i) {
    int idx = colsrc[base + i];
    float4 v = *(const float4*)&p[(size_t)idx * 64 + c4];
    s0.x += v.x; s0.y += v.y; s0.z += v.z; s0.w += v.w;
  }
  float r = 1.f / fmaxf((float)d, 1.f);
  float4 a = *(const float4*)&q[(size_t)node * 64 + c4];
  float4 b = *(const float4*)&b2[c4];
  float4 o;
  o.x = (s0.x + s1.x + s2.x + s3.x) * r + a.x + b.x;
  o.y = (s0.y + s1.y + s2.y + s3.y) * r + a.y + b.y;
  o.z = (s0.z + s1.z + s2.z + s3.z) * r + a.z + b.z;
  o.w = (s0.w + s1.w + s2.w + s3.w) * r + a.w + b.w;
  *(float4*)&out[(size_t)node * 64 + c4] = o;
}

extern "C" void kernel_launch(void* const* d_in, const int* in_sizes, int n_in,
                              void* d_out, int out_size, void* d_ws,
                              size_t ws_size, hipStream_t stream) {
  const float* x = (const float*)d_in[0];
  const int* ei = (const int*)d_in[1];
  const float* W1l = (const float*)d_in[2];
  const float* b1 = (const float*)d_in[3];
  const float* W1r = (const float*)d_in[4];
  const float* W2l = (const float*)d_in[5];
  const float* b2 = (const float*)d_in[6];
  const float* W2r = (const float*)d_in[7];
  float* out = (float*)d_out;

  const int N = in_sizes[0] / 64;  // 50000
  const int E = in_sizes[1] / 2;   // 800000
  const int* src = ei;
  const int* dst = ei + E;

  // ws: int deg[N] | int total[1] | rowptr[N] | pos[N] | colsrc[E+4N]
  //   | float p[N*64] | q[N*64]
  int* deg = (int*)d_ws;
  int* total = deg + N;
  int* rowptr = total + 1;
  int* pos = rowptr + N;
  int* colsrc = pos + N;
  float* p = (float*)(colsrc + (E + 4 * N));
  float* q = p + (size_t)N * 64;

  hipMemsetAsync(deg, 0, (size_t)(N + 1) * sizeof(int), stream);
  k_hist<<<(E + 255) / 256, 256, 0, stream>>>(dst, deg, E);
  k_assign<<<(N + 255) / 256, 256, 0, stream>>>(deg, rowptr, pos, total, N);
  k_fill<<<(E + 255) / 256, 256, 0, stream>>>(src, dst, pos, colsrc, E);

  int nblk64 = (N + 63) / 64;  // 782
  int nblk16 = (N + 15) / 16;  // 3125
  k_layer1<<<nblk64, 256, 0, stream>>>(x, rowptr, deg, colsrc, W1l, b1, W1r,
                                       W2l, W2r, p, q, N);
  k_layer2<<<nblk16, 256, 0, stream>>>(p, rowptr, deg, colsrc, q, b2, out, N);
}

// Round 10
// 326.351 us; speedup vs baseline: 1.1054x; 1.1054x over previous
//
#include <hip/hip_runtime.h>

// GraphSAGE 2-layer, N=50000, E=800000, 64 -> 128 -> 64, fp32.
//   h   = relu(mean_agg(x) @ W1_l + b1 + x @ W1_r)
//   out = mean_agg(h) @ W2_l + b2 + h @ W2_r
// R10: R9 structure, spill fixed. R9's __launch_bounds__(256,4) capped VGPR
// at 64 while the 8nx4j tile needs ~100 -> 190MB/dispatch scratch traffic
// (WRITE_SIZE 25->215MB). Now (256,2): VGPR cap 128, zero spill; 4 blocks/CU
// by both VGPR and LDS (34.8KB).
// Linearity: mean_agg(h)@W2_l = agg(h@W2_l)/cnt -> layer 2 gathers p = h@W2_l.

#define FMA4(acc, f, w0, w1, w2, w3)                          \
  acc.x += f.x * w0.x + f.y * w1.x + f.z * w2.x + f.w * w3.x; \
  acc.y += f.x * w0.y + f.y * w1.y + f.z * w2.y + f.w * w3.y; \
  acc.z += f.x * w0.z + f.y * w1.z + f.z * w2.z + f.w * w3.z; \
  acc.w += f.x * w0.w + f.y * w1.w + f.z * w2.w + f.w * w3.w;

// ---------------- CSR build (scan-free, 16B-aligned rows) ----------------
__global__ __launch_bounds__(256) void k_hist(const int* __restrict__ dst,
                                              int* __restrict__ deg, int E) {
  int e = blockIdx.x * blockDim.x + threadIdx.x;
  if (e < E) atomicAdd(&deg[dst[e]], 1);
}

__global__ __launch_bounds__(256) void k_assign(const int* __restrict__ deg,
                                                int* __restrict__ rowptr,
                                                int* __restrict__ pos,
                                                int* __restrict__ total,
                                                int N) {
  int i = blockIdx.x * blockDim.x + threadIdx.x;
  if (i >= N) return;
  int d4 = (deg[i] + 3) & ~3;  // 16B-aligned row
  int r = atomicAdd(total, d4);
  rowptr[i] = r;
  pos[i] = r;
}

__global__ __launch_bounds__(256) void k_fill(const int* __restrict__ src,
                                              const int* __restrict__ dst,
                                              int* __restrict__ pos,
                                              int* __restrict__ colsrc, int E) {
  int e = blockIdx.x * blockDim.x + threadIdx.x;
  if (e >= E) return;
  int slot = atomicAdd(&pos[dst[e]], 1);
  colsrc[slot] = src[e];
}

// ---------------------------------------------------------------------------
// layer1: 64 nodes/block, 256 threads.
//   gather (to LDS): 16-lane group per node (4 nodes/group serially); int4
//     index windows -> 8 independent row loads in flight; lane owns 4 cols.
//   phase1: thread (jt=tid&31, nt=tid>>5) -> 8n x 4j tile of h.
//   phase2: waves 0-1 p=h@W2l, waves 2-3 q=h@W2r; node = g2 + 8m interleave.
// LDS: ms[64][68]+xs[64][68] (34.8KB) overlaid by hs[64][132] (33.8KB).
// ---------------------------------------------------------------------------
__global__ __launch_bounds__(256, 2) void k_layer1(
    const float* __restrict__ x, const int* __restrict__ rowptr,
    const int* __restrict__ deg, const int* __restrict__ colsrc,
    const float* __restrict__ W1l, const float* __restrict__ b1,
    const float* __restrict__ W1r, const float* __restrict__ W2l,
    const float* __restrict__ W2r, float* __restrict__ p,
    float* __restrict__ q, int N) {
  int i0 = blockIdx.x * 64;
  int tid = threadIdx.x;
  __shared__ float smem[64 * 68 * 2];               // 34816 B
  float(*ms)[68] = (float(*)[68])smem;              // [64][68]
  float(*xs)[68] = (float(*)[68])(smem + 64 * 68);  // [64][68]
  float(*hs)[132] = (float(*)[132])smem;            // overlays after sync

  // ---- gather phase: mean -> ms (group of 16 lanes per node) ----
  {
    int grp = tid >> 4;             // 0..15
    int c4 = (tid & 15) << 2;       // 0,4,...,60
    for (int nn = 0; nn < 4; ++nn) {
      int nl = grp * 4 + nn;        // local node 0..63
      int node = i0 + nl;
      float4 s0 = make_float4(0.f, 0.f, 0.f, 0.f);
      float4 s1 = s0, s2 = s0, s3 = s0;
      float rd = 0.f;
      if (node < N) {
        int base = rowptr[node];
        int d = deg[node];
        rd = 1.f / fmaxf((float)d, 1.f);
        int i = 0;
        for (; i + 8 <= d; i += 8) {
          int4 ia = *(const int4*)&colsrc[base + i];
          int4 ib = *(const int4*)&colsrc[base + i + 4];
          float4 v0 = *(const float4*)&x[(size_t)ia.x * 64 + c4];
          float4 v1 = *(const float4*)&x[(size_t)ia.y * 64 + c4];
          float4 v2 = *(const float4*)&x[(size_t)ia.z * 64 + c4];
          float4 v3 = *(const float4*)&x[(size_t)ia.w * 64 + c4];
          float4 v4 = *(const float4*)&x[(size_t)ib.x * 64 + c4];
          float4 v5 = *(const float4*)&x[(size_t)ib.y * 64 + c4];
          float4 v6 = *(const float4*)&x[(size_t)ib.z * 64 + c4];
          float4 v7 = *(const float4*)&x[(size_t)ib.w * 64 + c4];
          s0.x += v0.x; s0.y += v0.y; s0.z += v0.z; s0.w += v0.w;
          s1.x += v1.x; s1.y += v1.y; s1.z += v1.z; s1.w += v1.w;
          s2.x += v2.x; s2.y += v2.y; s2.z += v2.z; s2.w += v2.w;
          s3.x += v3.x; s3.y += v3.y; s3.z += v3.z; s3.w += v3.w;
          s0.x += v4.x; s0.y += v4.y; s0.z += v4.z; s0.w += v4.w;
          s1.x += v5.x; s1.y += v5.y; s1.z += v5.z; s1.w += v5.w;
          s2.x += v6.x; s2.y += v6.y; s2.z += v6.z; s2.w += v6.w;
          s3.x += v7.x; s3.y += v7.y; s3.z += v7.z; s3.w += v7.w;
        }
        for (; i < d; ++i) {
          int idx = colsrc[base + i];
          float4 v = *(const float4*)&x[(size_t)idx * 64 + c4];
          s0.x += v.x; s0.y += v.y; s0.z += v.z; s0.w += v.w;
        }
      }
      s0.x = (s0.x + s1.x + s2.x + s3.x) * rd;
      s0.y = (s0.y + s1.y + s2.y + s3.y) * rd;
      s0.z = (s0.z + s1.z + s2.z + s3.z) * rd;
      s0.w = (s0.w + s1.w + s2.w + s3.w) * rd;
      *(float4*)&ms[nl][c4] = s0;
    }
  }
  // stage xs: 64 nodes x 16 float4 = 1024 float4 across 256 threads
  for (int t = tid; t < 1024; t += 256) {
    int n = t >> 4;
    int c4 = (t & 15) << 2;
    int node = i0 + n;
    float4 zx = make_float4(0.f, 0.f, 0.f, 0.f);
    if (node < N) zx = *(const float4*)&x[(size_t)node * 64 + c4];
    *(float4*)&xs[n][c4] = zx;
  }
  __syncthreads();

  // ---- phase 1: h tile (8 nodes x 4 cols per thread) ----
  int jt = tid & 31;
  int j0 = jt << 2;          // 0..124
  int nt = tid >> 5;
  int n0 = nt << 3;          // 0..56
  float4 acc[8];
  {
    float4 bj = *(const float4*)&b1[j0];
#pragma unroll
    for (int n = 0; n < 8; ++n) acc[n] = bj;
  }
#pragma unroll 2
  for (int k0 = 0; k0 < 64; k0 += 4) {
    float4 wl[4], wr[4];
#pragma unroll
    for (int kk = 0; kk < 4; ++kk) {
      wl[kk] = *(const float4*)&W1l[(size_t)(k0 + kk) * 128 + j0];
      wr[kk] = *(const float4*)&W1r[(size_t)(k0 + kk) * 128 + j0];
    }
#pragma unroll
    for (int n = 0; n < 8; ++n) {
      float4 m4 = *(const float4*)&ms[n0 + n][k0];
      float4 x4 = *(const float4*)&xs[n0 + n][k0];
      FMA4(acc[n], m4, wl[0], wl[1], wl[2], wl[3]);
      FMA4(acc[n], x4, wr[0], wr[1], wr[2], wr[3]);
    }
  }
  __syncthreads();  // ms/xs reads done before hs overlay

#pragma unroll
  for (int n = 0; n < 8; ++n) {
    float4 v = acc[n];
    v.x = fmaxf(v.x, 0.f);
    v.y = fmaxf(v.y, 0.f);
    v.z = fmaxf(v.z, 0.f);
    v.w = fmaxf(v.w, 0.f);
    *(float4*)&hs[n0 + n][j0] = v;
  }
  __syncthreads();

  // ---- phase 2: p = hs@W2l (waves 0-1), q = hs@W2r (waves 2-3) ----
  const float* W = (tid < 128) ? W2l : W2r;
  float* ob = (tid < 128) ? p : q;
  int t2 = tid & 127;
  int jj0 = (t2 & 15) << 2;  // 0..60
  int g2 = t2 >> 4;          // 0..7 ; nodes g2 + 8m (interleaved, bank-free)
  float4 pa[8];
#pragma unroll
  for (int n = 0; n < 8; ++n) pa[n] = make_float4(0.f, 0.f, 0.f, 0.f);
#pragma unroll 2
  for (int k0 = 0; k0 < 128; k0 += 4) {
    float4 w[4];
#pragma unroll
    for (int kk = 0; kk < 4; ++kk)
      w[kk] = *(const float4*)&W[(size_t)(k0 + kk) * 64 + jj0];
#pragma unroll
    for (int m = 0; m < 8; ++m) {
      float4 h4 = *(const float4*)&hs[g2 + 8 * m][k0];
      FMA4(pa[m], h4, w[0], w[1], w[2], w[3]);
    }
  }
#pragma unroll
  for (int m = 0; m < 8; ++m) {
    int node = i0 + g2 + 8 * m;
    if (node < N) *(float4*)&ob[(size_t)node * 64 + jj0] = pa[m];
  }
}

// ---------------------------------------------------------------------------
// layer2: out[node] = mean_agg(p)[node] + q[node] + b2.
// 16-lane group per node, int4 index windows, 8 row loads in flight.
// ---------------------------------------------------------------------------
__global__ __launch_bounds__(256) void k_layer2(
    const float* __restrict__ p, const int* __restrict__ rowptr,
    const int* __restrict__ deg, const int* __restrict__ colsrc,
    const float* __restrict__ q, const float* __restrict__ b2,
    float* __restrict__ out, int N) {
  int node = blockIdx.x * 16 + (threadIdx.x >> 4);
  if (node >= N) return;
  int c4 = (threadIdx.x & 15) << 2;
  int base = rowptr[node];
  int d = deg[node];
  float4 s0 = make_float4(0.f, 0.f, 0.f, 0.f);
  float4 s1 = s0, s2 = s0, s3 = s0;
  int i = 0;
  for (; i + 8 <= d; i += 8) {
    int4 ia = *(const int4*)&colsrc[base + i];
    int4 ib = *(const int4*)&colsrc[base + i + 4];
    float4 v0 = *(const float4*)&p[(size_t)ia.x * 64 + c4];
    float4 v1 = *(const float4*)&p[(size_t)ia.y * 64 + c4];
    float4 v2 = *(const float4*)&p[(size_t)ia.z * 64 + c4];
    float4 v3 = *(const float4*)&p[(size_t)ia.w * 64 + c4];
    float4 v4 = *(const float4*)&p[(size_t)ib.x * 64 + c4];
    float4 v5 = *(const float4*)&p[(size_t)ib.y * 64 + c4];
    float4 v6 = *(const float4*)&p[(size_t)ib.z * 64 + c4];
    float4 v7 = *(const float4*)&p[(size_t)ib.w * 64 + c4];
    s0.x += v0.x; s0.y += v0.y; s0.z += v0.z; s0.w += v0.w;
    s1.x += v1.x; s1.y += v1.y; s1.z += v1.z; s1.w += v1.w;
    s2.x += v2.x; s2.y += v2.y; s2.z += v2.z; s2.w += v2.w;
    s3.x += v3.x; s3.y += v3.y; s3.z += v3.z; s3.w += v3.w;
    s0.x += v4.x; s0.y += v4.y; s0.z += v4.z; s0.w += v4.w;
    s1.x += v5.x; s1.y += v5.y; s1.z += v5.z; s1.w += v5.w;
    s2.x += v6.x; s2.y += v6.y; s2.z += v6.z; s2.w += v6.w;
    s3.x += v7.x; s3.y += v7.y; s3.z += v7.z; s3.w += v7.w;
  }
  for (; i < d; ++i) {
    int idx = colsrc[base + i];
    float4 v = *(const float4*)&p[(size_t)idx * 64 + c4];
    s0.x += v.x; s0.y += v.y; s0.z += v.z; s0.w += v.w;
  }
  float r = 1.f / fmaxf((float)d, 1.f);
  float4 a = *(const float4*)&q[(size_t)node * 64 + c4];
  float4 b = *(const float4*)&b2[c4];
  float4 o;
  o.x = (s0.x + s1.x + s2.x + s3.x) * r + a.x + b.x;
  o.y = (s0.y + s1.y + s2.y + s3.y) * r + a.y + b.y;
  o.z = (s0.z + s1.z + s2.z + s3.z) * r + a.z + b.z;
  o.w = (s0.w + s1.w + s2.w + s3.w) * r + a.w + b.w;
  *(float4*)&out[(size_t)node * 64 + c4] = o;
}

extern "C" void kernel_launch(void* const* d_in, const int* in_sizes, int n_in,
                              void* d_out, int out_size, void* d_ws,
                              size_t ws_size, hipStream_t stream) {
  const float* x = (const float*)d_in[0];
  const int* ei = (const int*)d_in[1];
  const float* W1l = (const float*)d_in[2];
  const float* b1 = (const float*)d_in[3];
  const float* W1r = (const float*)d_in[4];
  const float* W2l = (const float*)d_in[5];
  const float* b2 = (const float*)d_in[6];
  const float* W2r = (const float*)d_in[7];
  float* out = (float*)d_out;

  const int N = in_sizes[0] / 64;  // 50000
  const int E = in_sizes[1] / 2;   // 800000
  const int* src = ei;
  const int* dst = ei + E;

  // ws: int deg[N] | int total[1] | rowptr[N] | pos[N] | colsrc[E+4N]
  //   | float p[N*64] | q[N*64]
  int* deg = (int*)d_ws;
  int* total = deg + N;
  int* rowptr = total + 1;
  int* pos = rowptr + N;
  int* colsrc = pos + N;
  float* p = (float*)(colsrc + (E + 4 * N));
  float* q = p + (size_t)N * 64;

  hipMemsetAsync(deg, 0, (size_t)(N + 1) * sizeof(int), stream);
  k_hist<<<(E + 255) / 256, 256, 0, stream>>>(dst, deg, E);
  k_assign<<<(N + 255) / 256, 256, 0, stream>>>(deg, rowptr, pos, total, N);
  k_fill<<<(E + 255) / 256, 256, 0, stream>>>(src, dst, pos, colsrc, E);

  int nblk64 = (N + 63) / 64;  // 782
  int nblk16 = (N + 15) / 16;  // 3125
  k_layer1<<<nblk64, 256, 0, stream>>>(x, rowptr, deg, colsrc, W1l, b1, W1r,
                                       W2l, W2r, p, q, N);
  k_layer2<<<nblk16, 256, 0, stream>>>(p, rowptr, deg, colsrc, q, b2, out, N);
}

// Round 11
// 311.174 us; speedup vs baseline: 1.1594x; 1.0488x over previous
//
#include <hip/hip_runtime.h>

// GraphSAGE 2-layer, N=50000, E=800000, 64 -> 128 -> 64, fp32.
//   h   = relu(mean_agg(x) @ W1_l + b1 + x @ W1_r)
//   out = mean_agg(h) @ W2_l + b2 + h @ W2_r
// R11: gathers are byte-bound on random 256B row reads (2 x 205 MB logical).
// Store gathered features fp16: x -> xh (k_cvt), p stored as ph (written
// fp16 in layer1 phase2). Row reads halve to 128B; accumulation stays fp32.
// Self-features xs and q remain fp32. Structure otherwise = R10 (no spill).
// Linearity: mean_agg(h)@W2_l = agg(h@W2_l)/cnt -> layer 2 gathers p = h@W2_l.

typedef __attribute__((ext_vector_type(4))) _Float16 half4_t;
typedef __attribute__((ext_vector_type(8))) _Float16 half8_t;

#define FMA4(acc, f, w0, w1, w2, w3)                          \
  acc.x += f.x * w0.x + f.y * w1.x + f.z * w2.x + f.w * w3.x; \
  acc.y += f.x * w0.y + f.y * w1.y + f.z * w2.y + f.w * w3.y; \
  acc.z += f.x * w0.z + f.y * w1.z + f.z * w2.z + f.w * w3.z; \
  acc.w += f.x * w0.w + f.y * w1.w + f.z * w2.w + f.w * w3.w;

#define ACC4H(s, v)       \
  s.x += (float)v[0];     \
  s.y += (float)v[1];     \
  s.z += (float)v[2];     \
  s.w += (float)v[3];

// ---------------- CSR build (scan-free, 16B-aligned rows) ----------------
__global__ __launch_bounds__(256) void k_hist(const int* __restrict__ dst,
                                              int* __restrict__ deg, int E) {
  int e = blockIdx.x * blockDim.x + threadIdx.x;
  if (e < E) atomicAdd(&deg[dst[e]], 1);
}

__global__ __launch_bounds__(256) void k_assign(const int* __restrict__ deg,
                                                int* __restrict__ rowptr,
                                                int* __restrict__ pos,
                                                int* __restrict__ total,
                                                int N) {
  int i = blockIdx.x * blockDim.x + threadIdx.x;
  if (i >= N) return;
  int d4 = (deg[i] + 3) & ~3;  // 16B-aligned row
  int r = atomicAdd(total, d4);
  rowptr[i] = r;
  pos[i] = r;
}

__global__ __launch_bounds__(256) void k_fill(const int* __restrict__ src,
                                              const int* __restrict__ dst,
                                              int* __restrict__ pos,
                                              int* __restrict__ colsrc, int E) {
  int e = blockIdx.x * blockDim.x + threadIdx.x;
  if (e >= E) return;
  int slot = atomicAdd(&pos[dst[e]], 1);
  colsrc[slot] = src[e];
}

// ---------------- x (fp32) -> xh (fp16), 8 elems/thread ----------------
__global__ __launch_bounds__(256) void k_cvt(const float* __restrict__ x,
                                             _Float16* __restrict__ xh,
                                             int total8) {
  int i = blockIdx.x * blockDim.x + threadIdx.x;
  if (i >= total8) return;
  float4 a = *(const float4*)&x[(size_t)i * 8];
  float4 b = *(const float4*)&x[(size_t)i * 8 + 4];
  half8_t h;
  h[0] = (_Float16)a.x; h[1] = (_Float16)a.y;
  h[2] = (_Float16)a.z; h[3] = (_Float16)a.w;
  h[4] = (_Float16)b.x; h[5] = (_Float16)b.y;
  h[6] = (_Float16)b.z; h[7] = (_Float16)b.w;
  *(half8_t*)&xh[(size_t)i * 8] = h;
}

// ---------------------------------------------------------------------------
// layer1: 64 nodes/block, 256 threads.
//   gather (to LDS): 16-lane group per node; int4 index windows -> 8
//     independent 128B fp16 row loads in flight; fp32 accumulate.
//   phase1: thread (jt, nt) -> 8n x 4j tile of h.
//   phase2: waves 0-1 p=h@W2l -> ph (fp16), waves 2-3 q=h@W2r -> q (fp32).
// LDS: ms[64][68]+xs[64][68] (34.8KB) overlaid by hs[64][132] (33.8KB).
// ---------------------------------------------------------------------------
__global__ __launch_bounds__(256, 2) void k_layer1(
    const float* __restrict__ x, const _Float16* __restrict__ xh,
    const int* __restrict__ rowptr, const int* __restrict__ deg,
    const int* __restrict__ colsrc, const float* __restrict__ W1l,
    const float* __restrict__ b1, const float* __restrict__ W1r,
    const float* __restrict__ W2l, const float* __restrict__ W2r,
    _Float16* __restrict__ ph, float* __restrict__ q, int N) {
  int i0 = blockIdx.x * 64;
  int tid = threadIdx.x;
  __shared__ float smem[64 * 68 * 2];               // 34816 B
  float(*ms)[68] = (float(*)[68])smem;              // [64][68]
  float(*xs)[68] = (float(*)[68])(smem + 64 * 68);  // [64][68]
  float(*hs)[132] = (float(*)[132])smem;            // overlays after sync

  // ---- gather phase: mean -> ms (16-lane group per node) ----
  {
    int grp = tid >> 4;        // 0..15
    int c4 = (tid & 15) << 2;  // half-offset 0,4,...,60
    for (int nn = 0; nn < 4; ++nn) {
      int nl = grp * 4 + nn;
      int node = i0 + nl;
      float4 s0 = make_float4(0.f, 0.f, 0.f, 0.f);
      float4 s1 = s0, s2 = s0, s3 = s0;
      float rd = 0.f;
      if (node < N) {
        int base = rowptr[node];
        int d = deg[node];
        rd = 1.f / fmaxf((float)d, 1.f);
        int i = 0;
        for (; i + 8 <= d; i += 8) {
          int4 ia = *(const int4*)&colsrc[base + i];
          int4 ib = *(const int4*)&colsrc[base + i + 4];
          half4_t v0 = *(const half4_t*)&xh[(size_t)ia.x * 64 + c4];
          half4_t v1 = *(const half4_t*)&xh[(size_t)ia.y * 64 + c4];
          half4_t v2 = *(const half4_t*)&xh[(size_t)ia.z * 64 + c4];
          half4_t v3 = *(const half4_t*)&xh[(size_t)ia.w * 64 + c4];
          half4_t v4 = *(const half4_t*)&xh[(size_t)ib.x * 64 + c4];
          half4_t v5 = *(const half4_t*)&xh[(size_t)ib.y * 64 + c4];
          half4_t v6 = *(const half4_t*)&xh[(size_t)ib.z * 64 + c4];
          half4_t v7 = *(const half4_t*)&xh[(size_t)ib.w * 64 + c4];
          ACC4H(s0, v0); ACC4H(s1, v1); ACC4H(s2, v2); ACC4H(s3, v3);
          ACC4H(s0, v4); ACC4H(s1, v5); ACC4H(s2, v6); ACC4H(s3, v7);
        }
        for (; i < d; ++i) {
          int idx = colsrc[base + i];
          half4_t v = *(const half4_t*)&xh[(size_t)idx * 64 + c4];
          ACC4H(s0, v);
        }
      }
      s0.x = (s0.x + s1.x + s2.x + s3.x) * rd;
      s0.y = (s0.y + s1.y + s2.y + s3.y) * rd;
      s0.z = (s0.z + s1.z + s2.z + s3.z) * rd;
      s0.w = (s0.w + s1.w + s2.w + s3.w) * rd;
      *(float4*)&ms[nl][c4] = s0;
    }
  }
  // stage xs (fp32 self-features)
  for (int t = tid; t < 1024; t += 256) {
    int n = t >> 4;
    int c4 = (t & 15) << 2;
    int node = i0 + n;
    float4 zx = make_float4(0.f, 0.f, 0.f, 0.f);
    if (node < N) zx = *(const float4*)&x[(size_t)node * 64 + c4];
    *(float4*)&xs[n][c4] = zx;
  }
  __syncthreads();

  // ---- phase 1: h tile (8 nodes x 4 cols per thread) ----
  int jt = tid & 31;
  int j0 = jt << 2;
  int nt = tid >> 5;
  int n0 = nt << 3;
  float4 acc[8];
  {
    float4 bj = *(const float4*)&b1[j0];
#pragma unroll
    for (int n = 0; n < 8; ++n) acc[n] = bj;
  }
#pragma unroll 2
  for (int k0 = 0; k0 < 64; k0 += 4) {
    float4 wl[4], wr[4];
#pragma unroll
    for (int kk = 0; kk < 4; ++kk) {
      wl[kk] = *(const float4*)&W1l[(size_t)(k0 + kk) * 128 + j0];
      wr[kk] = *(const float4*)&W1r[(size_t)(k0 + kk) * 128 + j0];
    }
#pragma unroll
    for (int n = 0; n < 8; ++n) {
      float4 m4 = *(const float4*)&ms[n0 + n][k0];
      float4 x4 = *(const float4*)&xs[n0 + n][k0];
      FMA4(acc[n], m4, wl[0], wl[1], wl[2], wl[3]);
      FMA4(acc[n], x4, wr[0], wr[1], wr[2], wr[3]);
    }
  }
  __syncthreads();  // ms/xs reads done before hs overlay

#pragma unroll
  for (int n = 0; n < 8; ++n) {
    float4 v = acc[n];
    v.x = fmaxf(v.x, 0.f);
    v.y = fmaxf(v.y, 0.f);
    v.z = fmaxf(v.z, 0.f);
    v.w = fmaxf(v.w, 0.f);
    *(float4*)&hs[n0 + n][j0] = v;
  }
  __syncthreads();

  // ---- phase 2: ph = h@W2l fp16 (waves 0-1), q = h@W2r fp32 (waves 2-3) ----
  bool isP = (tid < 128);
  const float* W = isP ? W2l : W2r;
  int t2 = tid & 127;
  int jj0 = (t2 & 15) << 2;
  int g2 = t2 >> 4;  // nodes g2 + 8m (interleaved, bank-free)
  float4 pa[8];
#pragma unroll
  for (int n = 0; n < 8; ++n) pa[n] = make_float4(0.f, 0.f, 0.f, 0.f);
#pragma unroll 2
  for (int k0 = 0; k0 < 128; k0 += 4) {
    float4 w[4];
#pragma unroll
    for (int kk = 0; kk < 4; ++kk)
      w[kk] = *(const float4*)&W[(size_t)(k0 + kk) * 64 + jj0];
#pragma unroll
    for (int m = 0; m < 8; ++m) {
      float4 h4 = *(const float4*)&hs[g2 + 8 * m][k0];
      FMA4(pa[m], h4, w[0], w[1], w[2], w[3]);
    }
  }
#pragma unroll
  for (int m = 0; m < 8; ++m) {
    int node = i0 + g2 + 8 * m;
    if (node >= N) continue;
    if (isP) {
      half4_t hv;
      hv[0] = (_Float16)pa[m].x;
      hv[1] = (_Float16)pa[m].y;
      hv[2] = (_Float16)pa[m].z;
      hv[3] = (_Float16)pa[m].w;
      *(half4_t*)&ph[(size_t)node * 64 + jj0] = hv;
    } else {
      *(float4*)&q[(size_t)node * 64 + jj0] = pa[m];
    }
  }
}

// ---------------------------------------------------------------------------
// layer2: out[node] = mean_agg(ph)[node] + q[node] + b2.
// 16-lane group per node, int4 index windows, fp16 rows, fp32 accumulate.
// ---------------------------------------------------------------------------
__global__ __launch_bounds__(256) void k_layer2(
    const _Float16* __restrict__ ph, const int* __restrict__ rowptr,
    const int* __restrict__ deg, const int* __restrict__ colsrc,
    const float* __restrict__ q, const float* __restrict__ b2,
    float* __restrict__ out, int N) {
  int node = blockIdx.x * 16 + (threadIdx.x >> 4);
  if (node >= N) return;
  int c4 = (threadIdx.x & 15) << 2;
  int base = rowptr[node];
  int d = deg[node];
  float4 s0 = make_float4(0.f, 0.f, 0.f, 0.f);
  float4 s1 = s0, s2 = s0, s3 = s0;
  int i = 0;
  for (; i + 8 <= d; i += 8) {
    int4 ia = *(const int4*)&colsrc[base + i];
    int4 ib = *(const int4*)&colsrc[base + i + 4];
    half4_t v0 = *(const half4_t*)&ph[(size_t)ia.x * 64 + c4];
    half4_t v1 = *(const half4_t*)&ph[(size_t)ia.y * 64 + c4];
    half4_t v2 = *(const half4_t*)&ph[(size_t)ia.z * 64 + c4];
    half4_t v3 = *(const half4_t*)&ph[(size_t)ia.w * 64 + c4];
    half4_t v4 = *(const half4_t*)&ph[(size_t)ib.x * 64 + c4];
    half4_t v5 = *(const half4_t*)&ph[(size_t)ib.y * 64 + c4];
    half4_t v6 = *(const half4_t*)&ph[(size_t)ib.z * 64 + c4];
    half4_t v7 = *(const half4_t*)&ph[(size_t)ib.w * 64 + c4];
    ACC4H(s0, v0); ACC4H(s1, v1); ACC4H(s2, v2); ACC4H(s3, v3);
    ACC4H(s0, v4); ACC4H(s1, v5); ACC4H(s2, v6); ACC4H(s3, v7);
  }
  for (; i < d; ++i) {
    int idx = colsrc[base + i];
    half4_t v = *(const half4_t*)&ph[(size_t)idx * 64 + c4];
    ACC4H(s0, v);
  }
  float r = 1.f / fmaxf((float)d, 1.f);
  float4 a = *(const float4*)&q[(size_t)node * 64 + c4];
  float4 b = *(const float4*)&b2[c4];
  float4 o;
  o.x = (s0.x + s1.x + s2.x + s3.x) * r + a.x + b.x;
  o.y = (s0.y + s1.y + s2.y + s3.y) * r + a.y + b.y;
  o.z = (s0.z + s1.z + s2.z + s3.z) * r + a.z + b.z;
  o.w = (s0.w + s1.w + s2.w + s3.w) * r + a.w + b.w;
  *(float4*)&out[(size_t)node * 64 + c4] = o;
}

extern "C" void kernel_launch(void* const* d_in, const int* in_sizes, int n_in,
                              void* d_out, int out_size, void* d_ws,
                              size_t ws_size, hipStream_t stream) {
  const float* x = (const float*)d_in[0];
  const int* ei = (const int*)d_in[1];
  const float* W1l = (const float*)d_in[2];
  const float* b1 = (const float*)d_in[3];
  const float* W1r = (const float*)d_in[4];
  const float* W2l = (const float*)d_in[5];
  const float* b2 = (const float*)d_in[6];
  const float* W2r = (const float*)d_in[7];
  float* out = (float*)d_out;

  const int N = in_sizes[0] / 64;  // 50000
  const int E = in_sizes[1] / 2;   // 800000
  const int* src = ei;
  const int* dst = ei + E;

  // 16B-aligned workspace carve-out
  char* base = (char*)d_ws;
  auto alloc = [&](size_t bytes) {
    char* r = base;
    base += (bytes + 15) & ~(size_t)15;
    return r;
  };
  int* deg = (int*)alloc((size_t)N * 4);
  int* total = (int*)alloc(4);
  int* rowptr = (int*)alloc((size_t)N * 4);
  int* pos = (int*)alloc((size_t)N * 4);
  int* colsrc = (int*)alloc((size_t)(E + 4 * N) * 4);
  _Float16* xh = (_Float16*)alloc((size_t)N * 64 * 2);
  _Float16* ph = (_Float16*)alloc((size_t)N * 64 * 2);
  float* q = (float*)alloc((size_t)N * 64 * 4);

  hipMemsetAsync(deg, 0, (size_t)N * sizeof(int), stream);
  hipMemsetAsync(total, 0, sizeof(int), stream);
  k_hist<<<(E + 255) / 256, 256, 0, stream>>>(dst, deg, E);
  k_assign<<<(N + 255) / 256, 256, 0, stream>>>(deg, rowptr, pos, total, N);
  k_fill<<<(E + 255) / 256, 256, 0, stream>>>(src, dst, pos, colsrc, E);
  k_cvt<<<(N * 8 + 255) / 256, 256, 0, stream>>>(x, xh, N * 8);

  int nblk64 = (N + 63) / 64;  // 782
  int nblk16 = (N + 15) / 16;  // 3125
  k_layer1<<<nblk64, 256, 0, stream>>>(x, xh, rowptr, deg, colsrc, W1l, b1,
                                       W1r, W2l, W2r, ph, q, N);
  k_layer2<<<nblk16, 256, 0, stream>>>(ph, rowptr, deg, colsrc, q, b2, out, N);
}

// Round 12
// 302.235 us; speedup vs baseline: 1.1936x; 1.0296x over previous
//
#include <hip/hip_runtime.h>

// GraphSAGE 2-layer, N=50000, E=800000, 64 -> 128 -> 64, fp32.
//   h   = relu(mean_agg(x) @ W1_l + b1 + x @ W1_r)
//   out = mean_agg(h) @ W2_l + b2 + h @ W2_r
// R12: gathers are latency-CHAIN bound (R11: bytes -30% -> time -2%). Fixes:
//  - CSR rows padded to 8 edges with index N; xh/ph have a zero row at N ->
//    tail loop eliminated (was ~3.5 serial full-latency iters per node).
//  - #pragma unroll 2 on gather window loops -> 2 windows software-pipelined
//    (16 row loads in flight, next window issues under current waits).
// Structure otherwise = R11 (fp16 gathered rows, fp32 accum, R10 dense tile).
// Linearity: mean_agg(h)@W2_l = agg(h@W2_l)/cnt -> layer 2 gathers p = h@W2_l.

typedef __attribute__((ext_vector_type(4))) _Float16 half4_t;
typedef __attribute__((ext_vector_type(8))) _Float16 half8_t;

#define FMA4(acc, f, w0, w1, w2, w3)                          \
  acc.x += f.x * w0.x + f.y * w1.x + f.z * w2.x + f.w * w3.x; \
  acc.y += f.x * w0.y + f.y * w1.y + f.z * w2.y + f.w * w3.y; \
  acc.z += f.x * w0.z + f.y * w1.z + f.z * w2.z + f.w * w3.z; \
  acc.w += f.x * w0.w + f.y * w1.w + f.z * w2.w + f.w * w3.w;

#define ACC4H(s, v)   \
  s.x += (float)v[0]; \
  s.y += (float)v[1]; \
  s.z += (float)v[2]; \
  s.w += (float)v[3];

// ---------------- CSR build (scan-free, rows padded to 8) ----------------
__global__ __launch_bounds__(256) void k_hist(const int* __restrict__ dst,
                                              int* __restrict__ deg, int E) {
  int e = blockIdx.x * blockDim.x + threadIdx.x;
  if (e < E) atomicAdd(&deg[dst[e]], 1);
}

__global__ __launch_bounds__(256) void k_assign(const int* __restrict__ deg,
                                                int* __restrict__ rowptr,
                                                int* __restrict__ pos,
                                                int* __restrict__ total,
                                                int N) {
  int i = blockIdx.x * blockDim.x + threadIdx.x;
  if (i >= N) return;
  int d8 = (deg[i] + 7) & ~7;  // 8-padded row
  int r = atomicAdd(total, d8);
  rowptr[i] = r;
  pos[i] = r;
}

// fill padding slots [base+d, base+d8) with N (the zero row index).
__global__ __launch_bounds__(256) void k_pad(const int* __restrict__ deg,
                                             const int* __restrict__ rowptr,
                                             int* __restrict__ colsrc, int N) {
  int i = blockIdx.x * blockDim.x + threadIdx.x;
  if (i >= N) return;
  int d = deg[i];
  int d8 = (d + 7) & ~7;
  int base = rowptr[i];
  for (int k = d; k < d8; ++k) colsrc[base + k] = N;
}

__global__ __launch_bounds__(256) void k_fill(const int* __restrict__ src,
                                              const int* __restrict__ dst,
                                              int* __restrict__ pos,
                                              int* __restrict__ colsrc, int E) {
  int e = blockIdx.x * blockDim.x + threadIdx.x;
  if (e >= E) return;
  int slot = atomicAdd(&pos[dst[e]], 1);
  colsrc[slot] = src[e];
}

// ---------------- x (fp32) -> xh (fp16), 8 elems/thread ----------------
__global__ __launch_bounds__(256) void k_cvt(const float* __restrict__ x,
                                             _Float16* __restrict__ xh,
                                             int total8) {
  int i = blockIdx.x * blockDim.x + threadIdx.x;
  if (i >= total8) return;
  float4 a = *(const float4*)&x[(size_t)i * 8];
  float4 b = *(const float4*)&x[(size_t)i * 8 + 4];
  half8_t h;
  h[0] = (_Float16)a.x; h[1] = (_Float16)a.y;
  h[2] = (_Float16)a.z; h[3] = (_Float16)a.w;
  h[4] = (_Float16)b.x; h[5] = (_Float16)b.y;
  h[6] = (_Float16)b.z; h[7] = (_Float16)b.w;
  *(half8_t*)&xh[(size_t)i * 8] = h;
}

// ---------------------------------------------------------------------------
// layer1: 64 nodes/block, 256 threads. Gather (padded, unroll-2 pipelined)
// -> ms; dense 8n x 4j tile; phase2 ph=h@W2l (fp16) / q=h@W2r (fp32).
// LDS: ms[64][68]+xs[64][68] (34.8KB) overlaid by hs[64][132] (33.8KB).
// ---------------------------------------------------------------------------
__global__ __launch_bounds__(256, 2) void k_layer1(
    const float* __restrict__ x, const _Float16* __restrict__ xh,
    const int* __restrict__ rowptr, const int* __restrict__ deg,
    const int* __restrict__ colsrc, const float* __restrict__ W1l,
    const float* __restrict__ b1, const float* __restrict__ W1r,
    const float* __restrict__ W2l, const float* __restrict__ W2r,
    _Float16* __restrict__ ph, float* __restrict__ q, int N) {
  int i0 = blockIdx.x * 64;
  int tid = threadIdx.x;
  __shared__ float smem[64 * 68 * 2];               // 34816 B
  float(*ms)[68] = (float(*)[68])smem;              // [64][68]
  float(*xs)[68] = (float(*)[68])(smem + 64 * 68);  // [64][68]
  float(*hs)[132] = (float(*)[132])smem;            // overlays after sync

  // ---- gather phase: mean -> ms (16-lane group per node) ----
  {
    int grp = tid >> 4;        // 0..15
    int c4 = (tid & 15) << 2;  // 0,4,...,60
    for (int nn = 0; nn < 4; ++nn) {
      int nl = grp * 4 + nn;
      int node = i0 + nl;
      float4 s0 = make_float4(0.f, 0.f, 0.f, 0.f);
      float4 s1 = s0, s2 = s0, s3 = s0;
      float rd = 0.f;
      if (node < N) {
        int base = rowptr[node];
        int d = deg[node];
        int d8 = (d + 7) & ~7;
        rd = 1.f / fmaxf((float)d, 1.f);
#pragma unroll 2
        for (int i = 0; i < d8; i += 8) {
          int4 ia = *(const int4*)&colsrc[base + i];
          int4 ib = *(const int4*)&colsrc[base + i + 4];
          half4_t v0 = *(const half4_t*)&xh[(size_t)ia.x * 64 + c4];
          half4_t v1 = *(const half4_t*)&xh[(size_t)ia.y * 64 + c4];
          half4_t v2 = *(const half4_t*)&xh[(size_t)ia.z * 64 + c4];
          half4_t v3 = *(const half4_t*)&xh[(size_t)ia.w * 64 + c4];
          half4_t v4 = *(const half4_t*)&xh[(size_t)ib.x * 64 + c4];
          half4_t v5 = *(const half4_t*)&xh[(size_t)ib.y * 64 + c4];
          half4_t v6 = *(const half4_t*)&xh[(size_t)ib.z * 64 + c4];
          half4_t v7 = *(const half4_t*)&xh[(size_t)ib.w * 64 + c4];
          ACC4H(s0, v0); ACC4H(s1, v1); ACC4H(s2, v2); ACC4H(s3, v3);
          ACC4H(s0, v4); ACC4H(s1, v5); ACC4H(s2, v6); ACC4H(s3, v7);
        }
      }
      s0.x = (s0.x + s1.x + s2.x + s3.x) * rd;
      s0.y = (s0.y + s1.y + s2.y + s3.y) * rd;
      s0.z = (s0.z + s1.z + s2.z + s3.z) * rd;
      s0.w = (s0.w + s1.w + s2.w + s3.w) * rd;
      *(float4*)&ms[nl][c4] = s0;
    }
  }
  // stage xs (fp32 self-features)
  for (int t = tid; t < 1024; t += 256) {
    int n = t >> 4;
    int c4 = (t & 15) << 2;
    int node = i0 + n;
    float4 zx = make_float4(0.f, 0.f, 0.f, 0.f);
    if (node < N) zx = *(const float4*)&x[(size_t)node * 64 + c4];
    *(float4*)&xs[n][c4] = zx;
  }
  __syncthreads();

  // ---- phase 1: h tile (8 nodes x 4 cols per thread) ----
  int jt = tid & 31;
  int j0 = jt << 2;
  int nt = tid >> 5;
  int n0 = nt << 3;
  float4 acc[8];
  {
    float4 bj = *(const float4*)&b1[j0];
#pragma unroll
    for (int n = 0; n < 8; ++n) acc[n] = bj;
  }
#pragma unroll 2
  for (int k0 = 0; k0 < 64; k0 += 4) {
    float4 wl[4], wr[4];
#pragma unroll
    for (int kk = 0; kk < 4; ++kk) {
      wl[kk] = *(const float4*)&W1l[(size_t)(k0 + kk) * 128 + j0];
      wr[kk] = *(const float4*)&W1r[(size_t)(k0 + kk) * 128 + j0];
    }
#pragma unroll
    for (int n = 0; n < 8; ++n) {
      float4 m4 = *(const float4*)&ms[n0 + n][k0];
      float4 x4 = *(const float4*)&xs[n0 + n][k0];
      FMA4(acc[n], m4, wl[0], wl[1], wl[2], wl[3]);
      FMA4(acc[n], x4, wr[0], wr[1], wr[2], wr[3]);
    }
  }
  __syncthreads();  // ms/xs reads done before hs overlay

#pragma unroll
  for (int n = 0; n < 8; ++n) {
    float4 v = acc[n];
    v.x = fmaxf(v.x, 0.f);
    v.y = fmaxf(v.y, 0.f);
    v.z = fmaxf(v.z, 0.f);
    v.w = fmaxf(v.w, 0.f);
    *(float4*)&hs[n0 + n][j0] = v;
  }
  __syncthreads();

  // ---- phase 2: ph = h@W2l fp16 (waves 0-1), q = h@W2r fp32 (waves 2-3) ----
  bool isP = (tid < 128);
  const float* W = isP ? W2l : W2r;
  int t2 = tid & 127;
  int jj0 = (t2 & 15) << 2;
  int g2 = t2 >> 4;  // nodes g2 + 8m (interleaved, bank-free)
  float4 pa[8];
#pragma unroll
  for (int n = 0; n < 8; ++n) pa[n] = make_float4(0.f, 0.f, 0.f, 0.f);
#pragma unroll 2
  for (int k0 = 0; k0 < 128; k0 += 4) {
    float4 w[4];
#pragma unroll
    for (int kk = 0; kk < 4; ++kk)
      w[kk] = *(const float4*)&W[(size_t)(k0 + kk) * 64 + jj0];
#pragma unroll
    for (int m = 0; m < 8; ++m) {
      float4 h4 = *(const float4*)&hs[g2 + 8 * m][k0];
      FMA4(pa[m], h4, w[0], w[1], w[2], w[3]);
    }
  }
#pragma unroll
  for (int m = 0; m < 8; ++m) {
    int node = i0 + g2 + 8 * m;
    if (node >= N) continue;
    if (isP) {
      half4_t hv;
      hv[0] = (_Float16)pa[m].x;
      hv[1] = (_Float16)pa[m].y;
      hv[2] = (_Float16)pa[m].z;
      hv[3] = (_Float16)pa[m].w;
      *(half4_t*)&ph[(size_t)node * 64 + jj0] = hv;
    } else {
      *(float4*)&q[(size_t)node * 64 + jj0] = pa[m];
    }
  }
}

// ---------------------------------------------------------------------------
// layer2: out[node] = mean_agg(ph)[node] + q[node] + b2.
// 16-lane group per node, padded rows, unroll-2 pipelined windows.
// ---------------------------------------------------------------------------
__global__ __launch_bounds__(256) void k_layer2(
    const _Float16* __restrict__ ph, const int* __restrict__ rowptr,
    const int* __restrict__ deg, const int* __restrict__ colsrc,
    const float* __restrict__ q, const float* __restrict__ b2,
    float* __restrict__ out, int N) {
  int node = blockIdx.x * 16 + (threadIdx.x >> 4);
  if (node >= N) return;
  int c4 = (threadIdx.x & 15) << 2;
  int base = rowptr[node];
  int d = deg[node];
  int d8 = (d + 7) & ~7;
  float4 s0 = make_float4(0.f, 0.f, 0.f, 0.f);
  float4 s1 = s0, s2 = s0, s3 = s0;
#pragma unroll 2
  for (int i = 0; i < d8; i += 8) {
    int4 ia = *(const int4*)&colsrc[base + i];
    int4 ib = *(const int4*)&colsrc[base + i + 4];
    half4_t v0 = *(const half4_t*)&ph[(size_t)ia.x * 64 + c4];
    half4_t v1 = *(const half4_t*)&ph[(size_t)ia.y * 64 + c4];
    half4_t v2 = *(const half4_t*)&ph[(size_t)ia.z * 64 + c4];
    half4_t v3 = *(const half4_t*)&ph[(size_t)ia.w * 64 + c4];
    half4_t v4 = *(const half4_t*)&ph[(size_t)ib.x * 64 + c4];
    half4_t v5 = *(const half4_t*)&ph[(size_t)ib.y * 64 + c4];
    half4_t v6 = *(const half4_t*)&ph[(size_t)ib.z * 64 + c4];
    half4_t v7 = *(const half4_t*)&ph[(size_t)ib.w * 64 + c4];
    ACC4H(s0, v0); ACC4H(s1, v1); ACC4H(s2, v2); ACC4H(s3, v3);
    ACC4H(s0, v4); ACC4H(s1, v5); ACC4H(s2, v6); ACC4H(s3, v7);
  }
  float r = 1.f / fmaxf((float)d, 1.f);
  float4 a = *(const float4*)&q[(size_t)node * 64 + c4];
  float4 b = *(const float4*)&b2[c4];
  float4 o;
  o.x = (s0.x + s1.x + s2.x + s3.x) * r + a.x + b.x;
  o.y = (s0.y + s1.y + s2.y + s3.y) * r + a.y + b.y;
  o.z = (s0.z + s1.z + s2.z + s3.z) * r + a.z + b.z;
  o.w = (s0.w + s1.w + s2.w + s3.w) * r + a.w + b.w;
  *(float4*)&out[(size_t)node * 64 + c4] = o;
}

extern "C" void kernel_launch(void* const* d_in, const int* in_sizes, int n_in,
                              void* d_out, int out_size, void* d_ws,
                              size_t ws_size, hipStream_t stream) {
  const float* x = (const float*)d_in[0];
  const int* ei = (const int*)d_in[1];
  const float* W1l = (const float*)d_in[2];
  const float* b1 = (const float*)d_in[3];
  const float* W1r = (const float*)d_in[4];
  const float* W2l = (const float*)d_in[5];
  const float* b2 = (const float*)d_in[6];
  const float* W2r = (const float*)d_in[7];
  float* out = (float*)d_out;

  const int N = in_sizes[0] / 64;  // 50000
  const int E = in_sizes[1] / 2;   // 800000
  const int* src = ei;
  const int* dst = ei + E;

  // 16B-aligned workspace carve-out
  char* base = (char*)d_ws;
  auto alloc = [&](size_t bytes) {
    char* r = base;
    base += (bytes + 15) & ~(size_t)15;
    return r;
  };
  int* deg = (int*)alloc((size_t)N * 4);
  int* total = (int*)alloc(4);
  int* rowptr = (int*)alloc((size_t)N * 4);
  int* pos = (int*)alloc((size_t)N * 4);
  int* colsrc = (int*)alloc((size_t)(E + 8 * N) * 4);
  _Float16* xh = (_Float16*)alloc((size_t)(N + 1) * 64 * 2);  // row N = zeros
  _Float16* ph = (_Float16*)alloc((size_t)(N + 1) * 64 * 2);  // row N = zeros
  float* q = (float*)alloc((size_t)N * 64 * 4);

  hipMemsetAsync(deg, 0, (size_t)N * sizeof(int), stream);
  hipMemsetAsync(total, 0, sizeof(int), stream);
  hipMemsetAsync(xh + (size_t)N * 64, 0, 64 * sizeof(_Float16), stream);
  hipMemsetAsync(ph + (size_t)N * 64, 0, 64 * sizeof(_Float16), stream);
  k_hist<<<(E + 255) / 256, 256, 0, stream>>>(dst, deg, E);
  k_assign<<<(N + 255) / 256, 256, 0, stream>>>(deg, rowptr, pos, total, N);
  k_pad<<<(N + 255) / 256, 256, 0, stream>>>(deg, rowptr, colsrc, N);
  k_fill<<<(E + 255) / 256, 256, 0, stream>>>(src, dst, pos, colsrc, E);
  k_cvt<<<(N * 8 + 255) / 256, 256, 0, stream>>>(x, xh, N * 8);

  int nblk64 = (N + 63) / 64;  // 782
  int nblk16 = (N + 15) / 16;  // 3125
  k_layer1<<<nblk64, 256, 0, stream>>>(x, xh, rowptr, deg, colsrc, W1l, b1,
                                       W1r, W2l, W2r, ph, q, N);
  k_layer2<<<nblk16, 256, 0, stream>>>(ph, rowptr, deg, colsrc, q, b2, out, N);
}